// Round 9
// baseline (245.310 us; speedup 1.0000x reference)
//
#include <hip/hip_runtime.h>

#define NB 512
#define NT 512
#define NL 64
#define L2E 1.4426950408889634f   // log2(e)
#define LN2 0.6931471805599453f   // ln(2)

typedef _Float16 h8v __attribute__((ext_vector_type(8)));
typedef _Float16 h4v __attribute__((ext_vector_type(4)));
typedef float    f4v __attribute__((ext_vector_type(4)));

__global__ void zero_out_kernel(float* out) { *out = 0.0f; }

// R9: MFMA step engine. One wave per batch (512 waves; R6 proved TLP >> ILP).
// State P (pre-em, raw f16, bounded 2^±8) in LDS state-major. Per step:
//   B = P ⊙ M   (M = eem*endfac*scale staged one step ahead in LDS, f16)
//   C = Eᵀ·B    (8x mfma_f32_16x16x32_f16; A-frags static in regs; B cols
//                replicated so C cols are identical)
//   P' = raw C  (4 active lanes scatter 64 states via 4x ds_write_b64)
// Rescale is an exact 2^(120-e0) folded into the NEXT staged M (off-chain);
// G accumulates e0-120 exactly. Lessons kept: no OCML calls (R5), 1 batch
// per wave (R6), f16 state (R7).
__global__
__attribute__((amdgpu_flat_work_group_size(64, 64), amdgpu_waves_per_eu(1, 1)))
void crf_nll_kernel(
    const float* __restrict__ emission,     // B,T,L
    const int*   __restrict__ target,       // B,T
    const float* __restrict__ mask,         // B,T
    const float* __restrict__ start_trans,  // L
    const float* __restrict__ trans,        // L,L
    const float* __restrict__ end_trans,    // L
    float* __restrict__ out)
{
  const int b = blockIdx.x;
  const int j = threadIdx.x;          // 0..63
  const int quad = j >> 4, col = j & 15;

  const float* em_b = emission + (size_t)b * NT * NL;
  const float* mk_b = mask + (size_t)b * NT;
  const int*   tg_b = target + (size_t)b * NT;

  // ---------------- path score (parallel over t, then wave-reduce) ----------
  float ps = 0.0f;
  #pragma unroll
  for (int c = 0; c < NT / 64; ++c) {
    int t = c * 64 + j;
    int cur = tg_b[t];
    float m  = mk_b[t];
    float mn = (t + 1 < NT) ? mk_b[t + 1] : 0.0f;
    if (t == 0) {
      ps += start_trans[cur] + em_b[cur];
    } else {
      int prev = tg_b[t - 1];
      if (m > 0.5f)
        ps += trans[prev * NL + cur] + em_b[(size_t)t * NL + cur];
      if (m - mn > 0.5f)                 // end_mask = m_t & !m_{t+1}
        ps += end_trans[cur];
    }
  }
  #pragma unroll
  for (int off = 32; off; off >>= 1) ps += __shfl_down(ps, off, 64);

  // -------- A-fragments: Eᵀ in exp2 domain, f16, static registers ----------
  // A_tile_T_half_H[m=col][k=8*quad+r (+32H)] = E[k][16T+col] = e^trans[k][16T+col]
  h8v A[4][2];
  #pragma unroll
  for (int T = 0; T < 4; ++T)
    #pragma unroll
    for (int H = 0; H < 2; ++H) {
      h8v a;
      #pragma unroll
      for (int r = 0; r < 8; ++r) {
        int k = 32 * H + 8 * quad + r;
        a[r] = (_Float16)__builtin_amdgcn_exp2f(L2E * trans[k * NL + 16 * T + col]);
      }
      A[T][H] = a;
    }
  const float endt = __builtin_amdgcn_exp2f(L2E * end_trans[j]);

  __shared__ __align__(16) _Float16 qp[NL];        // P, state-major
  __shared__ __align__(16) _Float16 est[4 * NL];   // M ring, 4 slots
  const char* estc = (const char*)est;

  // init: P = exp2(l2e*start) raw; M_0 = eem_0 (scale 1, no end at t=0)
  qp[j] = (_Float16)__builtin_amdgcn_exp2f(L2E * start_trans[j]);
  est[j] = (_Float16)__builtin_amdgcn_exp2f(L2E * em_b[j]);
  int pendOff = 0;                                 // byte offset of pending M
  int G = 0;                                       // exact log2 scale deficit

  // emission FIFO: pfem[t&7] holds em[t][j] (raw)
  float pfem[8];
  #pragma unroll
  for (int w = 0; w < 8; ++w) pfem[w] = em_b[(size_t)w * NL + j];

  const int qoff = 16 * quad;                      // B-frag byte offset

  #pragma unroll 1
  for (int c = 0; c < 8; ++c) {
    const int tb = c * 64;
    // per-chunk wave-uniform ballot masks
    float ml = mk_b[tb + j];
    int nidx = tb + j + 1;
    float mnext = (nidx < NT) ? mk_b[nidx] : 0.0f;
    unsigned long long cm = __ballot(ml > 0.5f);
    unsigned long long ce = __ballot(ml - mnext > 0.5f);
    if (c == 0) { cm &= ~1ull; ce &= ~1ull; }      // t=0 handled by init

    #pragma unroll 1
    for (int i8 = 0; i8 < 64; i8 += 8) {
      #pragma unroll
      for (int u = 0; u < 8; ++u) {
        const int i = i8 + u;
        const int t = tb + i;
        // FIFO reload (always)
        int tp = t + 8; if (tp > NT - 1) tp = NT - 1;
        float emload = em_b[(size_t)tp * NL + j];
        if (c == 0 && i8 == 0 && u == 0) { pfem[u] = emload; continue; } // t=0

        if ((cm >> i) & 1) {
          // ---- consume: B = P ⊙ M_pend, C = Eᵀ·B -------------------------
          h8v me1 = *(const h8v*)(estc + pendOff + qoff);
          h8v me2 = *(const h8v*)(estc + pendOff + qoff + 64);
          h8v q1  = *(const h8v*)((const char*)qp + qoff);
          h8v q2  = *(const h8v*)((const char*)qp + qoff + 64);
          h8v B1 = q1 * me1;
          h8v B2 = q2 * me2;
          f4v C0 = {0.f,0.f,0.f,0.f}, C1 = C0, C2 = C0, C3 = C0;
          C0 = __builtin_amdgcn_mfma_f32_16x16x32_f16(A[0][0], B1, C0, 0,0,0);
          C1 = __builtin_amdgcn_mfma_f32_16x16x32_f16(A[1][0], B1, C1, 0,0,0);
          C2 = __builtin_amdgcn_mfma_f32_16x16x32_f16(A[2][0], B1, C2, 0,0,0);
          C3 = __builtin_amdgcn_mfma_f32_16x16x32_f16(A[3][0], B1, C3, 0,0,0);
          C0 = __builtin_amdgcn_mfma_f32_16x16x32_f16(A[0][1], B2, C0, 0,0,0);
          C1 = __builtin_amdgcn_mfma_f32_16x16x32_f16(A[1][1], B2, C1, 0,0,0);
          C2 = __builtin_amdgcn_mfma_f32_16x16x32_f16(A[2][1], B2, C2, 0,0,0);
          C3 = __builtin_amdgcn_mfma_f32_16x16x32_f16(A[3][1], B2, C3, 0,0,0);
          // lane0 holds state 0 (tile0,reg0,col0): exponent-keyed rescale
          unsigned e0 =
            (__builtin_amdgcn_readfirstlane(__float_as_uint(C0[0])) >> 23) & 0xffu;
          float scale = __uint_as_float((247u - e0) << 23);   // 2^(120-e0)
          G += (int)e0 - 120;
          // ---- P' = raw C, scattered by the 4 col==0 lanes ---------------
          if (col == 0) {
            h4v w0, w1, w2, w3;
            w0[0]=(_Float16)C0[0]; w0[1]=(_Float16)C0[1]; w0[2]=(_Float16)C0[2]; w0[3]=(_Float16)C0[3];
            w1[0]=(_Float16)C1[0]; w1[1]=(_Float16)C1[1]; w1[2]=(_Float16)C1[2]; w1[3]=(_Float16)C1[3];
            w2[0]=(_Float16)C2[0]; w2[1]=(_Float16)C2[1]; w2[2]=(_Float16)C2[2]; w2[3]=(_Float16)C2[3];
            w3[0]=(_Float16)C3[0]; w3[1]=(_Float16)C3[1]; w3[2]=(_Float16)C3[2]; w3[3]=(_Float16)C3[3];
            *(h4v*)&qp[ 0 + 4 * quad] = w0;
            *(h4v*)&qp[16 + 4 * quad] = w1;
            *(h4v*)&qp[32 + 4 * quad] = w2;
            *(h4v*)&qp[48 + 4 * quad] = w3;
          }
          // ---- stage M_t = eem_t * endfac_t * scale_t (consumed at t+1) --
          float eem = __builtin_amdgcn_exp2f(L2E * pfem[u]);
          if ((ce >> i) & 1) eem *= endt;
          est[((t & 3) << 6) + j] = (_Float16)(eem * scale);
          pendOff = (t & 3) << 7;                  // bytes
        } else {
          // masked step: q_t = q_{t-1} * endt^{eb}; fold into P lane-locally
          if ((ce >> i) & 1) {
            float pv = (float)qp[j] * endt;
            qp[j] = (_Float16)pv;
          }
          // pend/M/G unchanged; no stage (pending slot stays valid)
        }
        pfem[u] = emload;
      }
    }
  }

  // ---------------- normalizer + output -------------------------------------
  float qfin = (float)qp[j] * (float)est[(pendOff >> 1) + j];
  #pragma unroll
  for (int off = 32; off; off >>= 1) qfin += __shfl_xor(qfin, off, 64);
  if (j == 0) {
    float norm = (__builtin_amdgcn_logf(qfin) + (float)G) * LN2;
    atomicAdd(out, (norm - ps) * (1.0f / (float)NB));
  }
}

extern "C" void kernel_launch(void* const* d_in, const int* in_sizes, int n_in,
                              void* d_out, int out_size, void* d_ws, size_t ws_size,
                              hipStream_t stream) {
  const float* emission    = (const float*)d_in[0];
  const int*   target      = (const int*)  d_in[1];
  const float* mask        = (const float*)d_in[2];
  const float* start_trans = (const float*)d_in[3];
  const float* trans       = (const float*)d_in[4];
  const float* end_trans   = (const float*)d_in[5];
  float* out = (float*)d_out;

  zero_out_kernel<<<1, 1, 0, stream>>>(out);
  crf_nll_kernel<<<NB, 64, 0, stream>>>(emission, target, mask, start_trans,
                                        trans, end_trans, out);
}

// Round 10
// 160.034 us; speedup vs baseline: 1.5329x; 1.5329x over previous
//
#include <hip/hip_runtime.h>

#define NB 512
#define NT 512
#define NL 64
#define L2E 1.4426950408889634f   // log2(e)
#define LN2 0.6931471805599453f   // ln(2)

typedef _Float16 h2 __attribute__((ext_vector_type(2)));
typedef _Float16 h8 __attribute__((ext_vector_type(8)));

__global__ void zero_out_kernel(float* out) { *out = 0.0f; }

__device__ __forceinline__ float dot2f(h2 a, h2 b, float c) {
#if __has_builtin(__builtin_amdgcn_fdot2)
  return __builtin_amdgcn_fdot2(a, b, c, false);
#else
  return fmaf((float)a[0], (float)b[0], fmaf((float)a[1], (float)b[1], c));
#endif
}

// R10: split the 512-step chain at T/2 into two INDEPENDENT 256-step
// recursions per batch (assoc. matrix-product chain):
//   wave 0 (fwd):  q   = (prod_{t<=255} M_t) q_0      q' = (E^T q) o eem
//   wave 1 (bwd):  v^T = 1^T (prod_{t>=256} M_t)      v' = E (v o eem o endf)
//   norm = log(v . q).
// 512 blocks x 128 thr -> 1024 waves -> 4 waves/CU (2x TLP) and HALF the
// serial steps per wave. Inner loop = R8's proven engine: f16 LDS broadcast,
// v_dot2_f32_f16, exact 2^(127-e0) exponent rescale, integer G. Lessons
// kept: no OCML calls (R5), TLP>>in-wave ILP (R6), f16+dot2 (R7), chain
// surgery (R8), no MFMA on chain (R9).
__global__
__attribute__((amdgpu_flat_work_group_size(128, 128), amdgpu_waves_per_eu(1, 1)))
void crf_nll_kernel(
    const float* __restrict__ emission,     // B,T,L
    const int*   __restrict__ target,       // B,T
    const float* __restrict__ mask,         // B,T
    const float* __restrict__ start_trans,  // L
    const float* __restrict__ trans,        // L,L
    const float* __restrict__ end_trans,    // L
    float* __restrict__ out)
{
  const int b = blockIdx.x;
  const int tid = threadIdx.x;
  const int wv = tid >> 6;            // 0 = forward, 1 = backward
  const int j = tid & 63;

  const float* em_b = emission + (size_t)b * NT * NL;
  const float* mk_b = mask + (size_t)b * NT;
  const int*   tg_b = target + (size_t)b * NT;

  __shared__ __align__(16) _Float16 qF[NL];   // fwd broadcast state
  __shared__ __align__(16) _Float16 qB[NL];   // bwd broadcast state
  __shared__ float fF[NL], fB[NL];            // final f32 states
  __shared__ float psS[2];
  __shared__ int   GS[2];

  // ------- path score: wave wv covers chunks [4wv, 4wv+4) = its T half -----
  float ps = 0.0f;
  #pragma unroll
  for (int c = 4 * wv; c < 4 * wv + 4; ++c) {
    int t = c * 64 + j;
    int cur = tg_b[t];
    float m  = mk_b[t];
    float mn = (t + 1 < NT) ? mk_b[t + 1] : 0.0f;
    if (t == 0) {
      ps += start_trans[cur] + em_b[cur];
    } else {
      int prev = tg_b[t - 1];
      if (m > 0.5f)
        ps += trans[prev * NL + cur] + em_b[(size_t)t * NL + cur];
      if (m - mn > 0.5f)                 // end_mask = m_t & !m_{t+1}
        ps += end_trans[cur];
    }
  }
  #pragma unroll
  for (int off = 32; off; off >>= 1) ps += __shfl_down(ps, off, 64);

  const float endt = __builtin_amdgcn_exp2f(L2E * end_trans[j]);

  int G = 0;          // exact integer scale deficit (log2 units): true = s*2^G
  float s;

  if (wv == 0) {
    // ======================= FORWARD: t = 0..255 ===========================
    // ep[k] = (E[2k][j], E[2k+1][j]) -- E column j, coalesced loads
    h2 ep[NL / 2];
    #pragma unroll
    for (int k = 0; k < NL / 2; ++k) {
      float e0 = __builtin_amdgcn_exp2f(L2E * trans[(2 * k + 0) * NL + j]);
      float e1 = __builtin_amdgcn_exp2f(L2E * trans[(2 * k + 1) * NL + j]);
      h2 v; v[0] = (_Float16)e0; v[1] = (_Float16)e1;
      ep[k] = v;
    }
    s = __builtin_amdgcn_exp2f(L2E * (start_trans[j] + em_b[j]));  // t=0
    qF[j] = (_Float16)s;                         // boot write (2^±8: f16 ok)
    const h8* qv = (const h8*)qF;

    float pf[8];
    #pragma unroll
    for (int u = 0; u < 8; ++u) pf[u] = L2E * em_b[(size_t)u * NL + j];

    #pragma unroll 1
    for (int c = 0; c < 4; ++c) {
      const int tb = c * 64;
      float ml = mk_b[tb + j];
      int nidx = tb + j + 1;
      float mnext = (nidx < NT) ? mk_b[nidx] : 0.0f;
      unsigned long long cm = __ballot(ml > 0.5f);
      unsigned long long ce = __ballot(ml - mnext > 0.5f);
      if (c == 0) { cm &= ~1ull; ce &= ~1ull; }  // t=0 handled by init

      #pragma unroll 1
      for (int i8 = 0; i8 < 64; i8 += 8) {
        #pragma unroll
        for (int u = 0; u < 8; ++u) {
          const int i = i8 + u;
          // off-chain: eem (endt folded), prefetch t+8
          float eemu = __builtin_amdgcn_exp2f(pf[u]);
          eemu = ((ce >> i) & 1) ? eemu * endt : eemu;
          int tp = tb + i + 8; if (tp > NT - 1) tp = NT - 1;
          pf[u] = L2E * em_b[(size_t)tp * NL + j];
          // chain: 8 reads -> 8-acc dot -> exp-rescale -> select -> write
          float a0 = 0.f, a1 = 0.f, a2 = 0.f, a3 = 0.f;
          float a4 = 0.f, a5 = 0.f, a6 = 0.f, a7 = 0.f;
          #pragma unroll
          for (int k = 0; k < 8; ++k) {
            h8 x = qv[k];
            h2 x0 = __builtin_shufflevector(x, x, 0, 1);
            h2 x1 = __builtin_shufflevector(x, x, 2, 3);
            h2 x2 = __builtin_shufflevector(x, x, 4, 5);
            h2 x3 = __builtin_shufflevector(x, x, 6, 7);
            if (k & 1) {
              a4 = dot2f(x0, ep[4 * k + 0], a4);
              a5 = dot2f(x1, ep[4 * k + 1], a5);
              a6 = dot2f(x2, ep[4 * k + 2], a6);
              a7 = dot2f(x3, ep[4 * k + 3], a7);
            } else {
              a0 = dot2f(x0, ep[4 * k + 0], a0);
              a1 = dot2f(x1, ep[4 * k + 1], a1);
              a2 = dot2f(x2, ep[4 * k + 2], a2);
              a3 = dot2f(x3, ep[4 * k + 3], a3);
            }
          }
          float sm = (((a0 + a4) + (a1 + a5)) + ((a2 + a6) + (a3 + a7)));
          unsigned e0 =
            (__builtin_amdgcn_readfirstlane(__float_as_uint(sm)) >> 23) & 0xffu;
          float scale = __uint_as_float((254u - e0) << 23);  // 2^(127-e0)
          float snew = (sm * scale) * eemu;
          float sold = s * scale;
          s = ((cm >> i) & 1) ? snew : sold;
          qF[j] = (_Float16)s;
          G += (int)e0 - 127;
        }
      }
    }
  } else {
    // ======================= BACKWARD: t = 511..256 ========================
    // epb[k] = (E[j][2k], E[j][2k+1]) -- E row j, contiguous per lane
    h2 epb[NL / 2];
    const float4* trow = (const float4*)(trans + (size_t)j * NL);
    #pragma unroll
    for (int k4 = 0; k4 < 16; ++k4) {
      float4 v4 = trow[k4];
      h2 p0; p0[0] = (_Float16)__builtin_amdgcn_exp2f(L2E * v4.x);
             p0[1] = (_Float16)__builtin_amdgcn_exp2f(L2E * v4.y);
      h2 p1; p1[0] = (_Float16)__builtin_amdgcn_exp2f(L2E * v4.z);
             p1[1] = (_Float16)__builtin_amdgcn_exp2f(L2E * v4.w);
      epb[2 * k4 + 0] = p0;
      epb[2 * k4 + 1] = p1;
    }
    s = 1.0f;                                   // v^T = 1^T
    const h8* qv = (const h8*)qB;

    float pf[8];                                 // pf[t&7] = l2e*em[t][j]
    #pragma unroll
    for (int u = 0; u < 8; ++u) pf[u] = L2E * em_b[(size_t)(504 + u) * NL + j];

    #pragma unroll 1
    for (int c = 7; c >= 4; --c) {
      const int tb = c * 64;
      float ml = mk_b[tb + j];
      int nidx = tb + j + 1;
      float mnext = (nidx < NT) ? mk_b[nidx] : 0.0f;
      unsigned long long cm = __ballot(ml > 0.5f);
      unsigned long long ce = __ballot(ml - mnext > 0.5f);

      #pragma unroll 1
      for (int i8 = 56; i8 >= 0; i8 -= 8) {
        #pragma unroll
        for (int u = 7; u >= 0; --u) {
          const int i = i8 + u;
          const int t = tb + i;                  // t & 7 == u
          // off-chain: wmul = eem^{m} * endt^{e}, prefetch t-8
          float eemu = __builtin_amdgcn_exp2f(pf[u]);
          float wmul = ((cm >> i) & 1) ? eemu : 1.0f;
          wmul = ((ce >> i) & 1) ? wmul * endt : wmul;
          int tp = t - 8; if (tp < 0) tp = 0;
          pf[u] = L2E * em_b[(size_t)tp * NL + j];
          // chain: w = s*wmul -> write -> 8 reads -> dot -> rescale
          float w = s * wmul;
          if ((cm >> i) & 1) {
            qB[j] = (_Float16)w;
            float a0 = 0.f, a1 = 0.f, a2 = 0.f, a3 = 0.f;
            float a4 = 0.f, a5 = 0.f, a6 = 0.f, a7 = 0.f;
            #pragma unroll
            for (int k = 0; k < 8; ++k) {
              h8 x = qv[k];
              h2 x0 = __builtin_shufflevector(x, x, 0, 1);
              h2 x1 = __builtin_shufflevector(x, x, 2, 3);
              h2 x2 = __builtin_shufflevector(x, x, 4, 5);
              h2 x3 = __builtin_shufflevector(x, x, 6, 7);
              if (k & 1) {
                a4 = dot2f(x0, epb[4 * k + 0], a4);
                a5 = dot2f(x1, epb[4 * k + 1], a5);
                a6 = dot2f(x2, epb[4 * k + 2], a6);
                a7 = dot2f(x3, epb[4 * k + 3], a7);
              } else {
                a0 = dot2f(x0, epb[4 * k + 0], a0);
                a1 = dot2f(x1, epb[4 * k + 1], a1);
                a2 = dot2f(x2, epb[4 * k + 2], a2);
                a3 = dot2f(x3, epb[4 * k + 3], a3);
              }
            }
            float sm = (((a0 + a4) + (a1 + a5)) + ((a2 + a6) + (a3 + a7)));
            unsigned e0 =
              (__builtin_amdgcn_readfirstlane(__float_as_uint(sm)) >> 23) & 0xffu;
            float scale = __uint_as_float((254u - e0) << 23);  // 2^(127-e0)
            s = sm * scale;
            G += (int)e0 - 127;
          } else {
            s = w;                               // A_t = I (masked-out step)
          }
        }
      }
    }
  }

  // ---------------- junction: norm = log(v . q) + (Gf+Gb)*ln2 ---------------
  if (wv == 0) { fF[j] = s; if (j == 0) { psS[0] = ps; GS[0] = G; } }
  else         { fB[j] = s; if (j == 0) { psS[1] = ps; GS[1] = G; } }
  __syncthreads();
  if (wv == 0) {
    float prod = s * fB[j];
    #pragma unroll
    for (int off = 32; off; off >>= 1) prod += __shfl_xor(prod, off, 64);
    if (j == 0) {
      float norm = (__builtin_amdgcn_logf(prod) + (float)(GS[0] + GS[1])) * LN2;
      atomicAdd(out, (norm - psS[0] - psS[1]) * (1.0f / (float)NB));
    }
  }
}

extern "C" void kernel_launch(void* const* d_in, const int* in_sizes, int n_in,
                              void* d_out, int out_size, void* d_ws, size_t ws_size,
                              hipStream_t stream) {
  const float* emission    = (const float*)d_in[0];
  const int*   target      = (const int*)  d_in[1];
  const float* mask        = (const float*)d_in[2];
  const float* start_trans = (const float*)d_in[3];
  const float* trans       = (const float*)d_in[4];
  const float* end_trans   = (const float*)d_in[5];
  float* out = (float*)d_out;

  zero_out_kernel<<<1, 1, 0, stream>>>(out);
  crf_nll_kernel<<<NB, 128, 0, stream>>>(emission, target, mask, start_trans,
                                         trans, end_trans, out);
}